// Round 7
// baseline (2865.631 us; speedup 1.0000x reference)
//
#include <hip/hip_runtime.h>

#define B_  128
#define T_  256
#define D_  256
#define U_  256
#define TU  768      // 3*U
#define TC  32       // timestep chunk
#define NC  (T_/TC)  // 8 chunks

__device__ __forceinline__ float sigm(float x) { return 1.f / (1.f + __expf(-x)); }

// direct cubic B-spline eval: grid cells [g_j, g_j+0.4), g_j = -2.2 + 0.4*j, j=0..10
__device__ __forceinline__ float spline_eval(float x, const float* __restrict__ ksw_lds, int u) {
    float xc = (x + 2.2f) * 2.5f;
    float fj = floorf(xc);
    int   j  = (int)fj;
    float tl = xc - fj;
    float t2 = tl * tl, t3 = t2 * tl;
    float om = 1.f - tl;
    const float S = 1.f / 6.f;
    float w0 = om * om * om * S;
    float w1 = (3.f * t3 - 6.f * t2 + 4.f) * S;
    float w2 = (-3.f * t3 + 3.f * t2 + 3.f * tl + 1.f) * S;
    float w3 = t3 * S;
    bool  v  = (j >= 0) && (j <= 10);
    float r  = 0.f;
#pragma unroll
    for (int k = 0; k < 4; ++k) {
        int   m  = j - 3 + k;
        bool  ok = v && (m >= 0) && (m <= 7);
        int   mc = min(max(m, 0), 7);
        float wk = (k == 0) ? w0 : (k == 1) ? w1 : (k == 2) ? w2 : w3;
        float cf = ksw_lds[u * 9 + mc];
        r += ok ? wk * cf : 0.f;
    }
    return r;
}

// swizzled LDS index for h[u]: chunk j of slice s lives at slot (j+s)&7 (bank-conflict-free
// for the 8 slice-groups reading their chunk-j float4 simultaneously)
__device__ __forceinline__ int hswz(int u) {
    int sw = u >> 5, jw = (u >> 2) & 7, m = u & 3;
    return (sw << 5) + (((jw + sw) & 7) << 2) + m;
}

// ---------------- K0: zero state + flags ----------------
__global__ void k0_init(float* __restrict__ wh, float* __restrict__ wc,
                        float* __restrict__ wsub, int* __restrict__ flags) {
    int i = blockIdx.x * 256 + threadIdx.x;
    wh[i] = 0.f;
    wc[i] = 0.f;
    if (i < 3 * B_) wsub[i] = 0.f;
    if (i < 2 * B_) flags[i] = -1;
}

// ---------------- K0c: convert+transpose R -> Rw bf16 [768 cols][256 rows] ----------------
__global__ __launch_bounds__(768) void k0_cvt(const float* __restrict__ R,
                                              unsigned short* __restrict__ Rw) {
    int u = blockIdx.x;          // 0..255 (row of R)
    int j = threadIdx.x;         // 0..767 (col)  -> coalesced read
    unsigned int bits = __float_as_uint(R[(size_t)u * TU + j]);
    unsigned int rn = (bits + 0x7fffu + ((bits >> 16) & 1u)) >> 16;   // RNE bf16
    Rw[(size_t)j * 256 + u] = (unsigned short)rn;
}

// ---------------- K1: A[b][tl][j] = x[b, t0+tl, :] @ kernel + bias ----------------
__global__ __launch_bounds__(256) void k1_gemm(const float* __restrict__ X,
                                               const float* __restrict__ Km,
                                               const float* __restrict__ bias,
                                               float* __restrict__ A, int t0) {
    __shared__ float Xs[16][68];
    __shared__ float Ks[16][68];
    const int bm  = blockIdx.x * 64;
    const int bn  = blockIdx.y * 64;
    const int tid = threadIdx.x;
    const int ty = tid >> 4, tx = tid & 15;

    const int lr  = tid >> 2;
    const int lk4 = (tid & 3) * 4;
    const int rr  = bm + lr;
    const int b   = rr / TC;
    const int tl  = rr % TC;
    const float* xrow = X + (size_t)(b * T_ + t0 + tl) * D_;

    const int kr  = tid >> 4;
    const int kn4 = (tid & 15) * 4;

    float acc[4][4] = {};
    for (int kb = 0; kb < 256; kb += 16) {
        float4 xv = *(const float4*)(xrow + kb + lk4);
        Xs[lk4 + 0][lr] = xv.x;
        Xs[lk4 + 1][lr] = xv.y;
        Xs[lk4 + 2][lr] = xv.z;
        Xs[lk4 + 3][lr] = xv.w;
        *(float4*)&Ks[kr][kn4] = *(const float4*)(Km + (size_t)(kb + kr) * TU + bn + kn4);
        __syncthreads();
#pragma unroll
        for (int k = 0; k < 16; ++k) {
            float4 av = *(float4*)&Xs[k][ty * 4];
            float4 bv = *(float4*)&Ks[k][tx * 4];
            acc[0][0] += av.x * bv.x; acc[0][1] += av.x * bv.y; acc[0][2] += av.x * bv.z; acc[0][3] += av.x * bv.w;
            acc[1][0] += av.y * bv.x; acc[1][1] += av.y * bv.y; acc[1][2] += av.y * bv.z; acc[1][3] += av.y * bv.w;
            acc[2][0] += av.z * bv.x; acc[2][1] += av.z * bv.y; acc[2][2] += av.z * bv.z; acc[2][3] += av.z * bv.w;
            acc[3][0] += av.w * bv.x; acc[3][1] += av.w * bv.y; acc[3][2] += av.w * bv.z; acc[3][3] += av.w * bv.w;
        }
        __syncthreads();
    }
    float4 bv = *(const float4*)(bias + bn + tx * 4);
#pragma unroll
    for (int i = 0; i < 4; ++i) {
        float4 o;
        o.x = acc[i][0] + bv.x; o.y = acc[i][1] + bv.y;
        o.z = acc[i][2] + bv.z; o.w = acc[i][3] + bv.w;
        *(float4*)(A + (size_t)(bm + ty * 4 + i) * TU + bn + tx * 4) = o;
    }
}

// ---- bf16 unpack (exact) ----
#define LOF(wv) __uint_as_float((wv) << 16)
#define HIF(wv) __uint_as_float((wv) & 0xffff0000u)
// one uint4 = 8 bf16 rows, consumed against two float4 h-chunks
#define MAC8(R4, hA, hB, acc) \
    acc = fmaf(LOF(R4.x), hA.x, acc); acc = fmaf(HIF(R4.x), hA.y, acc); \
    acc = fmaf(LOF(R4.y), hA.z, acc); acc = fmaf(HIF(R4.y), hA.w, acc); \
    acc = fmaf(LOF(R4.z), hB.x, acc); acc = fmaf(HIF(R4.z), hB.y, acc); \
    acc = fmaf(LOF(R4.w), hB.z, acc); acc = fmaf(HIF(R4.w), hB.w, acc);

// ---------------- K2: pair-split streaming recurrence (bf16 R) ----------------
// 256 blocks (b = idx&127, r = idx>>7) -> <=1 block/CU, co-residency GUARANTEED (spin-safe).
// Block owns 384 cols: j = g*256 + r*128 + c (g=0..2, c=0..127), output units ui = r*128 + c.
// Thread (q = tid>>3, s = tid&7): 4 cols (colL = 4q..4q+3), rows s*32..s*32+31.
// Per step per CU: 384x256 bf16 = 192 KB streamed from L2 (R1 measured 786 KB -> 8.5 us).
__global__ __launch_bounds__(768)
__attribute__((amdgpu_waves_per_eu(3, 3)))
void k2_rec(const float* __restrict__ A,
            const float* __restrict__ X,
            const unsigned short* __restrict__ Rw,   // [768][256] bf16
            const float* __restrict__ stk,
            const float* __restrict__ strk,
            const float* __restrict__ aggw,
            const float* __restrict__ aggb,
            const float* __restrict__ kbw,
            const float* __restrict__ ksw,
            float* __restrict__ out,
            float* __restrict__ ws_h,
            float* __restrict__ ws_c,
            float* __restrict__ ws_sub,
            float* __restrict__ xh,    // [B][2][256] fp32
            int* __restrict__ flags,   // [B][2]
            int t0) {
    __shared__ __align__(16) float hs[256];      // swizzled (hswz)
    __shared__ float xs[256];
    __shared__ float zfin[384];
    __shared__ float kred[768];
    __shared__ float so_l[3];
    __shared__ float subs[3];
    __shared__ float st2[6];
    __shared__ float ksw_lds[768 * 9];

    const int tid  = threadIdx.x;
    const int lane = tid & 63;
    const int w    = tid >> 6;         // wave 0..11
    const int q    = tid >> 3;         // col-quad 0..95
    const int s    = tid & 7;          // row-slice (32 rows)
    const int colL = q << 2;
    const int j0   = ((colL >> 7) << 8) + (blockIdx.x >> 7) * 128 + (colL & 127);
    const int u0   = s << 5;
    const int b    = blockIdx.x & 127;
    const int r    = blockIdx.x >> 7;

    // KAN stationary weights (one (s,d) eval per thread, as in R1)
    const int s0 = tid >> 8, d0 = tid & 255;
    const float skx0 = strk[s0 * 512 + d0];
    const float skh0 = strk[s0 * 512 + 256 + d0];
    const float bw0  = kbw[tid];

    // gate-owner state (tid<128)
    const int ui = r * 128 + tid;      // valid for tid<128
    float aw0 = 0.f, aw1 = 0.f, aw2 = 0.f, ab = 0.f, c_reg = 0.f;
    if (tid < 128) {
        aw0 = aggw[ui]; aw1 = aggw[256 + ui]; aw2 = aggw[512 + ui];
        ab  = aggb[ui];
        c_reg = ws_c[b * 256 + ui];
    }

    for (int i = tid; i < 768 * 8; i += 768) ksw_lds[(i >> 3) * 9 + (i & 7)] = ksw[i];
    if (tid < 256) hs[hswz(tid)] = ws_h[b * 256 + tid];
    if (tid < 3)   subs[tid] = ws_sub[b * 3 + tid];
    if (tid < 6)   st2[tid] = stk[tid];
    __syncthreads();

    const unsigned short* rp = Rw + ((size_t)j0 << 8) + u0;
    int* pflag = &flags[b * 2 + (1 - r)];

    for (int tl = 0; tl < TC; ++tl) {
        const int t = t0 + tl;

        // ---- phase1: A prefetch (s==0 threads, float4 over the quad) + stage x_t ----
        float4 az4 = make_float4(0.f, 0.f, 0.f, 0.f);
        if (s == 0) az4 = *(const float4*)(A + ((size_t)b * TC + tl) * TU + j0);
        if (tid < 256) xs[tid] = X[((size_t)b * T_ + t) * D_ + tid];
        __syncthreads();   // sync1

        // ---- phase2: KAN eval + partner h fetch (swizzled LDS write) ----
        {
            float a0 = xs[d0] * skx0 + subs[s0] * skh0;
            kred[tid] = a0 * sigm(a0) * bw0 + spline_eval(a0, ksw_lds, tid);
        }
        if (tl > 0 && tid < 128) {
            const int u = (1 - r) * 128 + tid;
            while (__hip_atomic_load(pflag, __ATOMIC_ACQUIRE, __HIP_MEMORY_SCOPE_AGENT) < t - 1) {}
            float hv = __hip_atomic_load(&xh[((size_t)b * 2 + ((t - 1) & 1)) * 256 + u],
                                         __ATOMIC_RELAXED, __HIP_MEMORY_SCOPE_AGENT);
            hs[hswz(u)] = hv;
        }
        __syncthreads();   // sync2

        // ---- phase3a: KAN reduce (waves 0-2) ----
        if (w < 3) {
            float v = kred[w * 256 + lane] + kred[w * 256 + 64 + lane]
                    + kred[w * 256 + 128 + lane] + kred[w * 256 + 192 + lane];
#pragma unroll
            for (int m = 32; m > 0; m >>= 1) v += __shfl_xor(v, m, 64);
            if (lane == 0) {
                so_l[w] = v;
                subs[w] = st2[w * 2] * v + st2[w * 2 + 1] * subs[w];
            }
        }

        // ---- phase3b: GEMV: 4 cols x 32 rows, bf16 R stream + broadcast h ----
        {
            // h chunks (conflict-free: 8 slice-groups hit 8 distinct slots)
            float4 h0 = *(const float4*)(hs + u0 + (((0 + s) & 7) << 2));
            float4 h1 = *(const float4*)(hs + u0 + (((1 + s) & 7) << 2));
            float4 h2 = *(const float4*)(hs + u0 + (((2 + s) & 7) << 2));
            float4 h3 = *(const float4*)(hs + u0 + (((3 + s) & 7) << 2));
            float4 h4 = *(const float4*)(hs + u0 + (((4 + s) & 7) << 2));
            float4 h5 = *(const float4*)(hs + u0 + (((5 + s) & 7) << 2));
            float4 h6 = *(const float4*)(hs + u0 + (((6 + s) & 7) << 2));
            float4 h7 = *(const float4*)(hs + u0 + (((7 + s) & 7) << 2));
            float acc0 = 0.f, acc1 = 0.f, acc2 = 0.f, acc3 = 0.f;
            {   // cols 0,1
                uint4 ra = *(const uint4*)(rp);
                uint4 rb = *(const uint4*)(rp + 8);
                uint4 rc = *(const uint4*)(rp + 16);
                uint4 rd = *(const uint4*)(rp + 24);
                uint4 re = *(const uint4*)(rp + 256);
                uint4 rf = *(const uint4*)(rp + 264);
                uint4 rg = *(const uint4*)(rp + 272);
                uint4 rh = *(const uint4*)(rp + 280);
                MAC8(ra, h0, h1, acc0) MAC8(rb, h2, h3, acc0)
                MAC8(rc, h4, h5, acc0) MAC8(rd, h6, h7, acc0)
                MAC8(re, h0, h1, acc1) MAC8(rf, h2, h3, acc1)
                MAC8(rg, h4, h5, acc1) MAC8(rh, h6, h7, acc1)
            }
            {   // cols 2,3
                uint4 ra = *(const uint4*)(rp + 512);
                uint4 rb = *(const uint4*)(rp + 520);
                uint4 rc = *(const uint4*)(rp + 528);
                uint4 rd = *(const uint4*)(rp + 536);
                uint4 re = *(const uint4*)(rp + 768);
                uint4 rf = *(const uint4*)(rp + 776);
                uint4 rg = *(const uint4*)(rp + 784);
                uint4 rh = *(const uint4*)(rp + 792);
                MAC8(ra, h0, h1, acc2) MAC8(rb, h2, h3, acc2)
                MAC8(rc, h4, h5, acc2) MAC8(rd, h6, h7, acc2)
                MAC8(re, h0, h1, acc3) MAC8(rf, h2, h3, acc3)
                MAC8(rg, h4, h5, acc3) MAC8(rh, h6, h7, acc3)
            }
            // reduce across the 8 row-slices (lanes s=0..7 within each 8-lane group)
            acc0 += __shfl_down(acc0, 4); acc0 += __shfl_down(acc0, 2); acc0 += __shfl_down(acc0, 1);
            acc1 += __shfl_down(acc1, 4); acc1 += __shfl_down(acc1, 2); acc1 += __shfl_down(acc1, 1);
            acc2 += __shfl_down(acc2, 4); acc2 += __shfl_down(acc2, 2); acc2 += __shfl_down(acc2, 1);
            acc3 += __shfl_down(acc3, 4); acc3 += __shfl_down(acc3, 2); acc3 += __shfl_down(acc3, 1);
            if (s == 0) {
                zfin[colL + 0] = az4.x + acc0;
                zfin[colL + 1] = az4.y + acc1;
                zfin[colL + 2] = az4.z + acc2;
                zfin[colL + 3] = az4.w + acc3;
            }
        }
        __syncthreads();   // sync3

        // ---- phase4: gates + state update + publish (tid<128) ----
        if (tid < 128) {
            float z0 = zfin[tid], z1 = zfin[128 + tid], z2 = zfin[256 + tid];
            float ig = sigm(z0);
            float fg = sigm(z1);
            c_reg = fg * c_reg + ig * tanhf(z2);
            float og = sigm(so_l[0] * aw0 + so_l[1] * aw1 + so_l[2] * aw2 + ab);
            float hn = og * tanhf(c_reg);
            hs[hswz(ui)] = hn;
            out[((size_t)b * T_ + t) * U_ + ui] = hn;
            if (tl < TC - 1) {
                __hip_atomic_store(&xh[((size_t)b * 2 + (t & 1)) * 256 + ui], hn,
                                   __ATOMIC_RELAXED, __HIP_MEMORY_SCOPE_AGENT);
            } else {
                ws_h[b * 256 + ui] = hn;
                ws_c[b * 256 + ui] = c_reg;
            }
        }
        __syncthreads();   // sync4 (drains the xh stores before flag release)
        if (tid == 0 && tl < TC - 1)
            __hip_atomic_store(&flags[b * 2 + r], t, __ATOMIC_RELEASE, __HIP_MEMORY_SCOPE_AGENT);
    }

    if (tid < 3) ws_sub[b * 3 + tid] = subs[tid];
}

extern "C" void kernel_launch(void* const* d_in, const int* in_sizes, int n_in,
                              void* d_out, int out_size, void* d_ws, size_t ws_size,
                              hipStream_t stream) {
    const float* x    = (const float*)d_in[0];
    const float* Kmat = (const float*)d_in[1];
    const float* R    = (const float*)d_in[2];
    const float* bias = (const float*)d_in[3];
    const float* stk  = (const float*)d_in[4];
    const float* strk = (const float*)d_in[5];
    const float* aggw = (const float*)d_in[6];
    const float* aggb = (const float*)d_in[7];
    const float* kbw  = (const float*)d_in[8];
    const float* ksw  = (const float*)d_in[9];
    float* out = (float*)d_out;

    float* ws   = (float*)d_ws;
    float* A    = ws;                                  // 128*32*768 = 3,145,728 f (12.6 MB)
    float* wh   = A + (size_t)B_ * TC * TU;            // 32768
    float* wc   = wh + B_ * U_;                        // 32768
    float* wsub = wc + B_ * U_;                        // 512 (padded)
    float* xh   = wsub + 512;                          // 65536
    int*   flg  = (int*)(xh + (size_t)B_ * 2 * 256);   // 512
    unsigned short* Rw = (unsigned short*)(flg + 512); // 196,608 ushorts (384 KB)
    // total ~13.4 MB (< the 24.6 MB envelope proven in R1-R5)

    k0_init<<<dim3(B_), dim3(256), 0, stream>>>(wh, wc, wsub, flg);
    k0_cvt<<<dim3(256), dim3(768), 0, stream>>>(R, Rw);
    for (int ci = 0; ci < NC; ++ci) {
        k1_gemm<<<dim3((B_ * TC) / 64, TU / 64), dim3(256), 0, stream>>>(x, Kmat, bias, A, ci * TC);
        k2_rec<<<dim3(2 * B_), dim3(768), 0, stream>>>(A, x, Rw, stk, strk, aggw, aggb, kbw, ksw,
                                                       out, wh, wc, wsub, xh, flg, ci * TC);
    }
}